// Round 1
// baseline (300.399 us; speedup 1.0000x reference)
//
#include <hip/hip_runtime.h>

// Problem constants (from reference)
constexpr int S  = 4096;   // N_SAMPLES
constexpr int W  = 16;     // N_WIDTH
constexpr int NN = 193;    // N_NODES
constexpr int DD = 2;      // NDIM_IN
constexpr int SW = S * W;                  // 65536
constexpr int PHI_OFF = 3 * SW;            // 196608 (after t, dt, ddt)
constexpr int PHI_SZ  = SW * NN * DD;      // 25,296,896 per tensor
constexpr int DX_OFF  = PHI_OFF + 3 * PHI_SZ;  // 76,087,296

// Row length per (i,k): 193 nodes * 2 dims = 386 floats = 193 float2
constexpr int ROW_F  = NN * DD;   // 386
constexpr int ROW_F2 = NN;        // 193 float2
constexpr int CHUNK_F2 = W * ROW_F2;  // 3088 float2 per (i, tensor)

__global__ __launch_bounds__(256)
void kan_fused_kernel(const float* __restrict__ x,
                      const float* __restrict__ w,
                      float* __restrict__ out) {
    const int i   = blockIdx.x;
    const int tid = threadIdx.x;

    // LDS: one 386-float row per output tensor (phi/dphi/ddphi), plus the
    // 4-per-dim basis values and left-node indices.
    __shared__ __align__(16) float row[3][ROW_F];   // 4632 B
    __shared__ float vals[3][DD][4];
    __shared__ int   nls[DD];

    // Phase 1a: zero the rows
    for (int idx = tid; idx < 3 * ROW_F; idx += 256)
        (&row[0][0])[idx] = 0.0f;

    // Phase 1b: threads 0,1 compute the Lagrange basis for dim d = tid
    if (tid < DD) {
        const int d = tid;
        float xv = x[i * DD + d];
        float xs = 192.0f * xv;                  // (N_NODES-1)*(x-xmin)/(xmax-xmin)
        float fe = floorf(xs / 3.0f);            // element index
        fe = fminf(fmaxf(fe, 0.0f), 63.0f);      // clip to [0, N_ELEMENTS-1]
        int nl = (int)(fe * 3.0f);               // left node index
        nls[d] = nl;
        float xr = 2.0f * (xs - (float)nl) / 3.0f - 1.0f;   // ref coord in [-1,1]

        // Cubic Lagrange basis at nodes {-1,-1/3,1/3,1}
        float xp1 = xr + 1.0f;
        float xm1 = xr - 1.0f;
        float x2  = xr * xr;
        float x2m = x2 - (1.0f / 9.0f);          // (x+1/3)(x-1/3)
        const float c0 = 0.5625f;                // 9/16
        const float c1 = 1.6875f;                // 27/16

        vals[0][d][0] = -c0 * x2m * xm1;
        vals[0][d][1] =  c1 * xp1 * (xr - (1.0f / 3.0f)) * xm1;
        vals[0][d][2] = -c1 * xp1 * (xr + (1.0f / 3.0f)) * xm1;
        vals[0][d][3] =  c0 * xp1 * x2m;

        const float idx1 = 128.0f;               // 1/delta_x (exact, 2^7)
        vals[1][d][0] = -c0 * (3.0f * x2 - 2.0f * xr - (1.0f / 9.0f)) * idx1;
        vals[1][d][1] =  c1 * (3.0f * x2 - (2.0f / 3.0f) * xr - 1.0f) * idx1;
        vals[1][d][2] = -c1 * (3.0f * x2 + (2.0f / 3.0f) * xr - 1.0f) * idx1;
        vals[1][d][3] =  c0 * (3.0f * x2 + 2.0f * xr - (1.0f / 9.0f)) * idx1;

        const float idx2 = 16384.0f;             // 1/delta_x^2 (exact, 2^14)
        vals[2][d][0] = -c0 * (6.0f * xr - 2.0f) * idx2;
        vals[2][d][1] =  c1 * (6.0f * xr - (2.0f / 3.0f)) * idx2;
        vals[2][d][2] = -c1 * (6.0f * xr + (2.0f / 3.0f)) * idx2;
        vals[2][d][3] =  c0 * (6.0f * xr + 2.0f) * idx2;
    }

    __syncthreads();

    // Phase 2a: scatter the 24 nonzero entries into the LDS rows
    if (tid < 24) {
        int a = tid >> 3;           // tensor 0..2
        int r = tid & 7;
        int d = r >> 2;             // dim 0..1
        int p = r & 3;              // local basis index 0..3
        row[a][(nls[d] + p) * DD + d] = vals[a][d][p];
    }

    // Phase 2b: t/dt/ddt dot products (independent of row[] — only needs vals/nls)
    if (tid < 48) {
        int k = tid / 3;            // width 0..15
        int a = tid % 3;            // tensor 0..2
        float s = 0.0f;
#pragma unroll
        for (int d = 0; d < DD; ++d) {
            int base = k * (NN * DD) + nls[d] * DD + d;
#pragma unroll
            for (int p = 0; p < 4; ++p)
                s += w[base + p * DD] * vals[a][d][p];
        }
        out[a * SW + i * W + k] = s;
    }

    if (i == 0 && tid == 0)
        out[DX_OFF] = 0.0078125f;   // delta_x

    __syncthreads();

    // Phase 3: stream the rows to global, 16 identical copies per tensor.
    // Store addresses are perfectly linear in idx (fully coalesced float2);
    // only the LDS read index needs idx mod 193.
#pragma unroll
    for (int a = 0; a < 3; ++a) {
        float2* dst = (float2*)(out + PHI_OFF + a * PHI_SZ) + (size_t)i * CHUNK_F2;
        const float2* src = (const float2*)(&row[a][0]);
        for (int idx = tid; idx < CHUNK_F2; idx += 256) {
            int j = idx % ROW_F2;   // magic-div by 193
            dst[idx] = src[j];
        }
    }
}

extern "C" void kernel_launch(void* const* d_in, const int* in_sizes, int n_in,
                              void* d_out, int out_size, void* d_ws, size_t ws_size,
                              hipStream_t stream) {
    const float* x = (const float*)d_in[0];   // (4096, 2) fp32
    const float* w = (const float*)d_in[1];   // (16, 193, 2) fp32
    float* out = (float*)d_out;

    kan_fused_kernel<<<S, 256, 0, stream>>>(x, w, out);
}